// Round 1
// baseline (1601.674 us; speedup 1.0000x reference)
//
#include <hip/hip_runtime.h>
#include <math.h>
#include <type_traits>

typedef float f2 __attribute__((ext_vector_type(2)));
typedef float f4 __attribute__((ext_vector_type(4)));

#define DD 160
#define HH 160
#define WW 160
#define BB 4
#define KK 11
#define RAD 5
#define TH 16
#define TW 16
#define DCH 32
#define NPLANES (DCH + 2 * RAD)   // 42 (loop padded to 44 = 4*11)
#define NDCH (DD / DCH)           // 5
#define HALO_H (TH + 2 * RAD)     // 26
#define TS 16                     // tmp row stride (scalar reads: 2 lanes/bank = free)
#define STAT (HALO_H * TS)        // 416 floats per stat plane

struct GaussW { float g[KK]; };

// 256 threads (4 waves), 1 scalar column per thread in phase 2 / D-ring.
// Ring state halves to 55 VGPRs/thread -> fits 128-reg budget -> 4 waves/SIMD.
__global__ __launch_bounds__(256, 4)
void ssim3d_kernel(const float* __restrict__ img1,
                   const float* __restrict__ img2,
                   float* __restrict__ out, GaussW gw)
{
    __shared__ float tmpA[5 * STAT];   // double buffer via pointer swap
    __shared__ float tmpB[5 * STAT];
    __shared__ float wsum[4];

    const int tid = threadIdx.x;        // 256 threads = 4 waves
    // phase-2 mapping: 16 rows x 16 cols, one scalar col per thread
    const int xc = tid & 15;
    const int ty = tid >> 4;
    // phase-1 mapping: 26 rows x 4 quads (threads 0..103 active, unchanged)
    const int p1r = tid >> 2;
    const int p1q = tid & 3;

    const int blk = blockIdx.x;
    const int bw = blk % 10;
    const int bh = (blk / 10) % 10;
    const int bd = (blk / 100) % NDCH;
    const int bb = blk / (100 * NDCH);

    const int oh0 = bh * TH, ow0 = bw * TW, od0 = bd * DCH;
    const float* base1 = img1 + (size_t)bb * DD * HH * WW;
    const float* base2 = img2 + (size_t)bb * DD * HH * WW;

    float g[KK];
#pragma unroll
    for (int i = 0; i < KK; ++i) g[i] = gw.g[i];

    // static D-ring: slot s holds output q with q % 11 == s (scalar, 1 col)
    float a1[KK], a2[KK], a11[KK], a22[KK], a12[KK];
#pragma unroll
    for (int i = 0; i < KK; ++i) { a1[i]=0.f; a2[i]=0.f; a11[i]=0.f; a22[i]=0.f; a12[i]=0.f; }

    float lsum = 0.f;

    // phase-1 per-thread constants
    const int gh = oh0 - RAD + p1r;
    const bool p1act = (p1r < HALO_H);
    const bool rowok = p1act && ((unsigned)gh < (unsigned)HH);
    const int gc0 = ow0 + 4 * p1q - 8;                    // first loaded col (16B aligned)
    const size_t rowoff = (size_t)((unsigned)gh < (unsigned)HH ? gh : 0) * WW;

    // prefetch registers for the next plane's 20 cols per thread
    f4 pa[5], pb[5];
#pragma unroll
    for (int j = 0; j < 5; ++j) { pa[j] = (f4)0.f; pb[j] = (f4)0.f; }

    float* twr = tmpA;   // buffer written (and read) this plane
    float* trd = tmpB;   // buffer of the previous plane

    // preamble: prefetch plane p=0 if valid
    {
        const int dn = od0 - RAD;
        if (p1act && (unsigned)dn < (unsigned)DD) {
            const size_t pbv = (size_t)dn * (HH * WW) + rowoff;
#pragma unroll
            for (int j = 0; j < 5; ++j) {
                const int gc = gc0 + 4 * j;
                f4 za = (f4)0.f, zb = (f4)0.f;
                if (rowok && gc >= 0 && gc <= WW - 4) {
                    za = *(const f4*)(base1 + pbv + gc);
                    zb = *(const f4*)(base2 + pbv + gc);
                }
                pa[j] = za; pb[j] = zb;
            }
        }
    }

    int pcbase = 0;
    auto body = [&](auto uc) {
        constexpr int U = decltype(uc)::value;
        const int p = pcbase + U;
        const int d = od0 - RAD + p;
        const bool dval = (p < NPLANES) && ((unsigned)d < (unsigned)DD);  // block-uniform

        // ---- phase 1: W-conv of 5 stats from prefetched regs (threads 0..103) ----
        if (dval && p1act) {
            float t1[4]  = {0.f,0.f,0.f,0.f};
            float t2[4]  = {0.f,0.f,0.f,0.f};
            float t11[4] = {0.f,0.f,0.f,0.f};
            float t22[4] = {0.f,0.f,0.f,0.f};
            float t12[4] = {0.f,0.f,0.f,0.f};
#pragma unroll
            for (int j = 0; j < 5; ++j) {
#pragma unroll
                for (int ii = 0; ii < 4; ++ii) {
                    const int i = 4 * j + ii;          // local col 0..19; need 3..16
                    if (i < 3 || i > 16) continue;
                    const float av = pa[j][ii], bv = pb[j][ii];
                    const float aa = av * av, bb2 = bv * bv, ab = av * bv;
#pragma unroll
                    for (int m = 0; m < 4; ++m) {
                        const int k = i - m - 3;       // tap index
                        if (k >= 0 && k < KK) {
                            const float w = g[k];
                            t1[m]  += w * av;
                            t2[m]  += w * bv;
                            t11[m] += w * aa;
                            t22[m] += w * bb2;
                            t12[m] += w * ab;
                        }
                    }
                }
            }
            float* tw = twr + p1r * TS + 4 * p1q;      // 16B-aligned
            f4 v;
            v[0]=t1[0];  v[1]=t1[1];  v[2]=t1[2];  v[3]=t1[3];  *(f4*)(tw + 0*STAT) = v;
            v[0]=t2[0];  v[1]=t2[1];  v[2]=t2[2];  v[3]=t2[3];  *(f4*)(tw + 1*STAT) = v;
            v[0]=t11[0]; v[1]=t11[1]; v[2]=t11[2]; v[3]=t11[3]; *(f4*)(tw + 2*STAT) = v;
            v[0]=t22[0]; v[1]=t22[1]; v[2]=t22[2]; v[3]=t22[3]; *(f4*)(tw + 3*STAT) = v;
            v[0]=t12[0]; v[1]=t12[1]; v[2]=t12[2]; v[3]=t12[3]; *(f4*)(tw + 4*STAT) = v;
        }

        // ---- prefetch plane p+1 (completes behind the barrier + phase 2) ----
        {
            const int pn = p + 1;
            const int dn = od0 - RAD + pn;
            if (p1act && (pn < NPLANES) && ((unsigned)dn < (unsigned)DD)) {
                const size_t pbv = (size_t)dn * (HH * WW) + rowoff;
#pragma unroll
                for (int j = 0; j < 5; ++j) {
                    const int gc = gc0 + 4 * j;
                    f4 za = (f4)0.f, zb = (f4)0.f;
                    if (rowok && gc >= 0 && gc <= WW - 4) {
                        za = *(const f4*)(base1 + pbv + gc);
                        zb = *(const f4*)(base2 + pbv + gc);
                    }
                    pa[j] = za; pb[j] = zb;
                }
            }
        }

        // ---- phase 2: H-conv (scalar, 2-way bank = free) + static-slot D scatter ----
        if (dval) {
            __syncthreads();   // only barrier per plane (dbuf pointer swap covers WAR)
            float P1 = 0.f, P2 = 0.f, P11 = 0.f, P22 = 0.f, P12 = 0.f;
            const float* tb = twr + (ty * TS + xc);
#pragma unroll
            for (int k = 0; k < KK; ++k) {
                const float w = g[k];
                const int o = k * TS;
                P1  += w * tb[0*STAT + o];
                P2  += w * tb[1*STAT + o];
                P11 += w * tb[2*STAT + o];
                P22 += w * tb[3*STAT + o];
                P12 += w * tb[4*STAT + o];
            }
#pragma unroll
            for (int t = 0; t < KK; ++t) {
                constexpr int base = U + 22;
                const int s = (base - t) % 11;         // folds: U, t compile-time
                const float w = g[t];
                a1[s]  += w * P1;
                a2[s]  += w * P2;
                a11[s] += w * P11;
                a22[s] += w * P22;
                a12[s] += w * P12;
            }
        }

        // ---- emit output q = p-10 from fixed slot (U+1)%11, then zero it ----
        constexpr int e = (U + 1) % 11;
        if (p >= 2 * RAD && p < NPLANES) {
            float mu1 = a1[e], mu2 = a2[e];
            float m11 = mu1 * mu1, m22 = mu2 * mu2, m12 = mu1 * mu2;
            float sg1 = a11[e] - m11, sg2 = a22[e] - m22, sg12 = a12[e] - m12;
            const float C1c = 0.0001f, C2c = 0.0009f;
            float num = (2.f * m12 + C1c) * (2.f * sg12 + C2c);
            float den = (m11 + m22 + C1c) * (sg1 + sg2 + C2c);
            lsum += num / den;
        }
        a1[e] = 0.f; a2[e] = 0.f; a11[e] = 0.f; a22[e] = 0.f; a12[e] = 0.f;

        // swap double buffers
        float* t = twr; twr = trd; trd = t;
    };

    for (pcbase = 0; pcbase < 44; pcbase += 11) {
        body(std::integral_constant<int, 0>{});
        body(std::integral_constant<int, 1>{});
        body(std::integral_constant<int, 2>{});
        body(std::integral_constant<int, 3>{});
        body(std::integral_constant<int, 4>{});
        body(std::integral_constant<int, 5>{});
        body(std::integral_constant<int, 6>{});
        body(std::integral_constant<int, 7>{});
        body(std::integral_constant<int, 8>{});
        body(std::integral_constant<int, 9>{});
        body(std::integral_constant<int, 10>{});
    }

    // ---- reduction: wave shuffle -> LDS -> one atomic per block ----
    float v = lsum;
#pragma unroll
    for (int off = 32; off > 0; off >>= 1)
        v += __shfl_down(v, off, 64);
    if ((tid & 63) == 0) wsum[tid >> 6] = v;
    __syncthreads();
    if (tid == 0) {
        const float inv_n = 1.0f / ((float)BB * DD * HH * WW);
        atomicAdd(out, (wsum[0] + wsum[1] + wsum[2] + wsum[3]) * inv_n);
    }
}

extern "C" void kernel_launch(void* const* d_in, const int* in_sizes, int n_in,
                              void* d_out, int out_size, void* d_ws, size_t ws_size,
                              hipStream_t stream) {
    const float* img1 = (const float*)d_in[0];
    const float* img2 = (const float*)d_in[1];
    float* out = (float*)d_out;

    GaussW gw;
    double gd[KK], sum = 0.0;
    for (int i = 0; i < KK; ++i) {
        double x = (double)(i - KK / 2);
        gd[i] = exp(-(x * x) / (2.0 * 1.5 * 1.5));
        sum += gd[i];
    }
    for (int i = 0; i < KK; ++i) gw.g[i] = (float)(gd[i] / sum);

    hipMemsetAsync(d_out, 0, sizeof(float), stream);

    dim3 grid(10 * 10 * NDCH * BB);   // 2000 blocks
    dim3 block(256);                  // 4 waves
    hipLaunchKernelGGL(ssim3d_kernel, grid, block, 0, stream,
                       img1, img2, out, gw);
}

// Round 2
// 1483.619 us; speedup vs baseline: 1.0796x; 1.0796x over previous
//
#include <hip/hip_runtime.h>
#include <math.h>
#include <type_traits>

typedef float f4 __attribute__((ext_vector_type(4)));

#define DD 160
#define HH 160
#define WW 160
#define BB 4
#define KK 11
#define RAD 5
#define TH 16
#define TW 16
#define DCH 32
#define NPLANES (DCH + 2 * RAD)   // 42 (loop padded to 44 = 4*11)
#define NDCH (DD / DCH)           // 5
#define HALO_H (TH + 2 * RAD)     // 26
#define TS 16                     // tmp row stride (phase-2 scalar reads: 2-way = free)
#define STAT (HALO_H * TS)        // 416 floats per stat plane
#define NSLOT 416                 // real 16B slots per raw buffer (2 imgs * 26 rows * 8 quads)
#define RAWF 2048                 // floats per raw buffer (512 slots, padded)

struct GaussW { float g[KK]; };

// 256 threads (4 waves). Scalar D-ring (55 regs). Raw staging via global_load_lds
// (no prefetch VGPRs); weights read from kernarg SGPRs. Target: <=128 regs -> 4 waves/SIMD.
__global__ __launch_bounds__(256, 4)
void ssim3d_kernel(const float* __restrict__ img1,
                   const float* __restrict__ img2,
                   float* __restrict__ out, GaussW gw)
{
    __shared__ __align__(16) float raw[2 * RAWF];    // raw-plane dbuf, quad-XOR swizzled
    __shared__ __align__(16) float tmpA[5 * STAT];   // W-conv result dbuf
    __shared__ __align__(16) float tmpB[5 * STAT];
    __shared__ float wsum[4];

    const int tid = threadIdx.x;        // 256 threads = 4 waves
    // phase-2 mapping: 16 rows x 16 cols, one scalar col per thread
    const int xc = tid & 15;
    const int ty = tid >> 4;
    // phase-1 mapping: 26 rows x 4 quads (threads 0..103 active)
    const int p1r = tid >> 2;
    const int p1q = tid & 3;

    const int blk = blockIdx.x;
    const int bw = blk % 10;
    const int bh = (blk / 10) % 10;
    const int bd = (blk / 100) % NDCH;
    const int bb = blk / (100 * NDCH);

    const int oh0 = bh * TH, ow0 = bw * TW, od0 = bd * DCH;
    const float* base1 = img1 + (size_t)bb * DD * HH * WW;
    const float* base2 = img2 + (size_t)bb * DD * HH * WW;

    // static D-ring: slot s holds output q with q % 11 == s (scalar, 1 col/thread)
    float a1[KK], a2[KK], a11[KK], a22[KK], a12[KK];
#pragma unroll
    for (int i = 0; i < KK; ++i) { a1[i]=0.f; a2[i]=0.f; a11[i]=0.f; a22[i]=0.f; a12[i]=0.f; }

    float lsum = 0.f;

    // ---- staging slot decode: slot s = c*256 + tid -> (img, row, swizzled quad) ----
    // LDS layout (linear in slot): [img][row 0..25][qs 0..7], 16B per slot.
    // Stored quad position qs holds SOURCE quad q = qs ^ (row&7)  (XOR involution;
    // phase-1 reads with the same XOR -> bank-balanced ds_read_b128).
    int sgok[2], sgimg[2], sgoff[2];
#pragma unroll
    for (int c = 0; c < 2; ++c) {
        const int s = tid + 256 * c;
        const int im = (s >= 208) ? 1 : 0;
        const int t = s - 208 * im;
        const int r = t >> 3;                 // row 0..25 (for s < 416)
        const int q = (t & 7) ^ (r & 7);      // source quad
        const int ghs = oh0 - RAD + r;
        const int gcs = ow0 - 8 + 4 * q;
        const bool ok = (s < NSLOT) && ((unsigned)ghs < (unsigned)HH)
                        && ((unsigned)gcs <= (unsigned)(WW - 4));
        sgok[c]  = ok ? 1 : 0;
        sgimg[c] = im;
        sgoff[c] = ok ? (ghs * WW + gcs) : 0;
    }

    auto stage = [&](int pn, int dn) {
        const int bufo = (pn & 1) * RAWF;
#pragma unroll
        for (int c = 0; c < 2; ++c) {
            float* lb = raw + bufo + c * 1024 + (tid & 192) * 4;   // wave-uniform base
            if (sgok[c]) {
                const float* gp = (sgimg[c] ? base2 : base1)
                                  + (size_t)dn * (HH * WW) + sgoff[c];
                __builtin_amdgcn_global_load_lds(
                    (const __attribute__((address_space(1))) void*)gp,
                    (__attribute__((address_space(3))) void*)lb, 16, 0, 0);
            }
        }
    };

    // pre-zero raw: OOB slots are never staged -> stay zero = implicit zero padding
#pragma unroll
    for (int w = 0; w < 4; ++w)
        *(f4*)(raw + 4 * tid + 1024 * w) = (f4)0.f;

    // preamble: stage plane p=0 (buffer 0) if its d is valid
    {
        const int dn = od0 - RAD;
        if ((unsigned)dn < (unsigned)DD) stage(0, dn);
    }
    __syncthreads();   // pre-zero visible + plane-0 loads drained before first use

    float* twr = tmpA;   // tmp buffer written (and read) this plane
    float* trd = tmpB;   // previous plane's buffer

    int pcbase = 0;
    auto body = [&](auto uc) {
        constexpr int U = decltype(uc)::value;
        const int p = pcbase + U;
        const int d = od0 - RAD + p;
        const bool dval = (p < NPLANES) && ((unsigned)d < (unsigned)DD);  // block-uniform

        // ---- issue async staging of plane p+1 into raw[(p+1)&1] (overlaps phase 1) ----
        {
            const int pn = p + 1;
            const int dn = od0 - RAD + pn;
            if ((pn < NPLANES) && ((unsigned)dn < (unsigned)DD)) stage(pn, dn);
        }

        // ---- phase 1: W-conv of 5 stats from LDS raw (threads 0..103) ----
        if (dval && p1r < HALO_H) {
            const int rswz = p1r & 7;
            const float* r1 = raw + (p & 1) * RAWF + p1r * 32;   // img1 row base
            const float* r2 = r1 + 832;                          // img2 block (+208 slots)
            float t1[4]  = {0.f,0.f,0.f,0.f};
            float t2[4]  = {0.f,0.f,0.f,0.f};
            float t11[4] = {0.f,0.f,0.f,0.f};
            float t22[4] = {0.f,0.f,0.f,0.f};
            float t12[4] = {0.f,0.f,0.f,0.f};
#pragma unroll
            for (int j = 0; j < 5; ++j) {
                const int qo = ((p1q + j) ^ rswz) << 2;          // swizzled quad, floats
                const f4 va = *(const f4*)(r1 + qo);
                const f4 vb = *(const f4*)(r2 + qo);
#pragma unroll
                for (int ii = 0; ii < 4; ++ii) {
                    const int i = 4 * j + ii;          // window col 0..19; need 3..16
                    if (i < 3 || i > 16) continue;
                    const float av = va[ii], bv = vb[ii];
                    const float aa = av * av, bb2 = bv * bv, ab = av * bv;
#pragma unroll
                    for (int m = 0; m < 4; ++m) {
                        const int k = i - m - 3;       // tap index (compile-time)
                        if (k >= 0 && k < KK) {
                            const float w = gw.g[k];   // SGPR (kernarg)
                            t1[m]  += w * av;
                            t2[m]  += w * bv;
                            t11[m] += w * aa;
                            t22[m] += w * bb2;
                            t12[m] += w * ab;
                        }
                    }
                }
            }
            float* tw = twr + p1r * TS + 4 * p1q;      // 16B-aligned
            f4 v;
            v[0]=t1[0];  v[1]=t1[1];  v[2]=t1[2];  v[3]=t1[3];  *(f4*)(tw + 0*STAT) = v;
            v[0]=t2[0];  v[1]=t2[1];  v[2]=t2[2];  v[3]=t2[3];  *(f4*)(tw + 1*STAT) = v;
            v[0]=t11[0]; v[1]=t11[1]; v[2]=t11[2]; v[3]=t11[3]; *(f4*)(tw + 2*STAT) = v;
            v[0]=t22[0]; v[1]=t22[1]; v[2]=t22[2]; v[3]=t22[3]; *(f4*)(tw + 3*STAT) = v;
            v[0]=t12[0]; v[1]=t12[1]; v[2]=t12[2]; v[3]=t12[3]; *(f4*)(tw + 4*STAT) = v;
        }

        // unconditional: tmp write->read ordering AND drains staged loads (vmcnt(0))
        __syncthreads();

        // ---- phase 2: H-conv (scalar) + static-slot D scatter ----
        if (dval) {
            float P1 = 0.f, P2 = 0.f, P11 = 0.f, P22 = 0.f, P12 = 0.f;
            const float* tb = twr + (ty * TS + xc);
#pragma unroll
            for (int k = 0; k < KK; ++k) {
                const float w = gw.g[k];
                const int o = k * TS;
                P1  += w * tb[0*STAT + o];
                P2  += w * tb[1*STAT + o];
                P11 += w * tb[2*STAT + o];
                P22 += w * tb[3*STAT + o];
                P12 += w * tb[4*STAT + o];
            }
#pragma unroll
            for (int t = 0; t < KK; ++t) {
                constexpr int base = U + 22;
                const int s = (base - t) % 11;         // compile-time fold
                const float w = gw.g[t];
                a1[s]  += w * P1;
                a2[s]  += w * P2;
                a11[s] += w * P11;
                a22[s] += w * P22;
                a12[s] += w * P12;
            }
        }

        // ---- emit output q = p-10 from fixed slot (U+1)%11, then zero it ----
        constexpr int e = (U + 1) % 11;
        if (p >= 2 * RAD && p < NPLANES) {
            float mu1 = a1[e], mu2 = a2[e];
            float m11 = mu1 * mu1, m22 = mu2 * mu2, m12 = mu1 * mu2;
            float sg1 = a11[e] - m11, sg2 = a22[e] - m22, sg12 = a12[e] - m12;
            const float C1c = 0.0001f, C2c = 0.0009f;
            float num = (2.f * m12 + C1c) * (2.f * sg12 + C2c);
            float den = (m11 + m22 + C1c) * (sg1 + sg2 + C2c);
            lsum += num / den;
        }
        a1[e] = 0.f; a2[e] = 0.f; a11[e] = 0.f; a22[e] = 0.f; a12[e] = 0.f;

        // swap tmp double buffers
        float* t = twr; twr = trd; trd = t;
    };

    for (pcbase = 0; pcbase < 44; pcbase += 11) {
        body(std::integral_constant<int, 0>{});
        body(std::integral_constant<int, 1>{});
        body(std::integral_constant<int, 2>{});
        body(std::integral_constant<int, 3>{});
        body(std::integral_constant<int, 4>{});
        body(std::integral_constant<int, 5>{});
        body(std::integral_constant<int, 6>{});
        body(std::integral_constant<int, 7>{});
        body(std::integral_constant<int, 8>{});
        body(std::integral_constant<int, 9>{});
        body(std::integral_constant<int, 10>{});
    }

    // ---- reduction: wave shuffle -> LDS -> one atomic per block ----
    float v = lsum;
#pragma unroll
    for (int off = 32; off > 0; off >>= 1)
        v += __shfl_down(v, off, 64);
    if ((tid & 63) == 0) wsum[tid >> 6] = v;
    __syncthreads();
    if (tid == 0) {
        const float inv_n = 1.0f / ((float)BB * DD * HH * WW);
        atomicAdd(out, (wsum[0] + wsum[1] + wsum[2] + wsum[3]) * inv_n);
    }
}

extern "C" void kernel_launch(void* const* d_in, const int* in_sizes, int n_in,
                              void* d_out, int out_size, void* d_ws, size_t ws_size,
                              hipStream_t stream) {
    const float* img1 = (const float*)d_in[0];
    const float* img2 = (const float*)d_in[1];
    float* out = (float*)d_out;

    GaussW gw;
    double gd[KK], sum = 0.0;
    for (int i = 0; i < KK; ++i) {
        double x = (double)(i - KK / 2);
        gd[i] = exp(-(x * x) / (2.0 * 1.5 * 1.5));
        sum += gd[i];
    }
    for (int i = 0; i < KK; ++i) gw.g[i] = (float)(gd[i] / sum);

    hipMemsetAsync(d_out, 0, sizeof(float), stream);

    dim3 grid(10 * 10 * NDCH * BB);   // 2000 blocks
    dim3 block(256);                  // 4 waves
    hipLaunchKernelGGL(ssim3d_kernel, grid, block, 0, stream,
                       img1, img2, out, gw);
}

// Round 3
// 403.182 us; speedup vs baseline: 3.9726x; 3.6798x over previous
//
#include <hip/hip_runtime.h>
#include <math.h>
#include <type_traits>

typedef float f4 __attribute__((ext_vector_type(4)));

#define DD 160
#define HH 160
#define WW 160
#define BB 4
#define KK 11
#define RAD 5
#define TH 16
#define TW 16
#define DCH 32
#define NPLANES (DCH + 2 * RAD)   // 42 (loop padded to 44 = 4*11)
#define NDCH (DD / DCH)           // 5
#define HALO_H (TH + 2 * RAD)     // 26
#define TS 16                     // tmp row stride (phase-2 scalar reads: 2-way = free)
#define STAT (HALO_H * TS)        // 416 floats per stat plane
#define NSLOT 416                 // real 16B slots per raw buffer (2 imgs * 26 rows * 8 quads)
#define RAWF 2048                 // floats per raw buffer (512 slots, padded)

struct GaussW { float g[KK]; };

// 256 threads (4 waves). Scalar D-ring (55 regs). Raw staging via global_load_lds.
// NOTE on launch bounds: (256,4) makes the backend cap ArchVGPRs at 64 -> catastrophic
// scratch spill (measured R1/R2: WRITE_SIZE 3.5-3.9 GB). (256,2) caps at 128; the live
// set (~105) fits -> no spill, and total <=128 regs gives 4 waves/SIMD naturally.
__global__ __launch_bounds__(256, 2)
void ssim3d_kernel(const float* __restrict__ img1,
                   const float* __restrict__ img2,
                   float* __restrict__ out, GaussW gw)
{
    __shared__ __align__(16) float raw[2 * RAWF];    // raw-plane dbuf, quad-XOR swizzled
    __shared__ __align__(16) float tmpA[5 * STAT];   // W-conv result dbuf
    __shared__ __align__(16) float tmpB[5 * STAT];
    __shared__ float wsum[4];

    const int tid = threadIdx.x;        // 256 threads = 4 waves
    // phase-2 mapping: 16 rows x 16 cols, one scalar col per thread
    const int xc = tid & 15;
    const int ty = tid >> 4;
    // phase-1 mapping: 26 rows x 4 quads (threads 0..103 active)
    const int p1r = tid >> 2;
    const int p1q = tid & 3;

    const int blk = blockIdx.x;
    const int bw = blk % 10;
    const int bh = (blk / 10) % 10;
    const int bd = (blk / 100) % NDCH;
    const int bb = blk / (100 * NDCH);

    const int oh0 = bh * TH, ow0 = bw * TW, od0 = bd * DCH;
    const float* base1 = img1 + (size_t)bb * DD * HH * WW;
    const float* base2 = img2 + (size_t)bb * DD * HH * WW;

    // static D-ring: slot s holds output q with q % 11 == s (scalar, 1 col/thread)
    float a1[KK], a2[KK], a11[KK], a22[KK], a12[KK];
#pragma unroll
    for (int i = 0; i < KK; ++i) { a1[i]=0.f; a2[i]=0.f; a11[i]=0.f; a22[i]=0.f; a12[i]=0.f; }

    float lsum = 0.f;

    // ---- staging slot decode: slot s = c*256 + tid -> (img, row, swizzled quad) ----
    // LDS layout (linear in slot): [img][row 0..25][qs 0..7], 16B per slot.
    // Stored quad position qs holds SOURCE quad q = qs ^ (row&7)  (XOR involution;
    // phase-1 reads with the same XOR -> bank-balanced ds_read_b128).
    int sgok[2], sgimg[2], sgoff[2];
#pragma unroll
    for (int c = 0; c < 2; ++c) {
        const int s = tid + 256 * c;
        const int im = (s >= 208) ? 1 : 0;
        const int t = s - 208 * im;
        const int r = t >> 3;                 // row 0..25 (for s < 416)
        const int q = (t & 7) ^ (r & 7);      // source quad
        const int ghs = oh0 - RAD + r;
        const int gcs = ow0 - 8 + 4 * q;
        const bool ok = (s < NSLOT) && ((unsigned)ghs < (unsigned)HH)
                        && ((unsigned)gcs <= (unsigned)(WW - 4));
        sgok[c]  = ok ? 1 : 0;
        sgimg[c] = im;
        sgoff[c] = ok ? (ghs * WW + gcs) : 0;
    }

    auto stage = [&](int pn, int dn) {
        const int bufo = (pn & 1) * RAWF;
#pragma unroll
        for (int c = 0; c < 2; ++c) {
            float* lb = raw + bufo + c * 1024 + (tid & 192) * 4;   // wave-uniform base
            if (sgok[c]) {
                const float* gp = (sgimg[c] ? base2 : base1)
                                  + (size_t)dn * (HH * WW) + sgoff[c];
                __builtin_amdgcn_global_load_lds(
                    (const __attribute__((address_space(1))) void*)gp,
                    (__attribute__((address_space(3))) void*)lb, 16, 0, 0);
            }
        }
    };

    // pre-zero raw: OOB slots are never staged -> stay zero = implicit zero padding
#pragma unroll
    for (int w = 0; w < 4; ++w)
        *(f4*)(raw + 4 * tid + 1024 * w) = (f4)0.f;

    // preamble: stage plane p=0 (buffer 0) if its d is valid
    {
        const int dn = od0 - RAD;
        if ((unsigned)dn < (unsigned)DD) stage(0, dn);
    }
    __syncthreads();   // pre-zero visible + plane-0 loads drained before first use

    float* twr = tmpA;   // tmp buffer written (and read) this plane
    float* trd = tmpB;   // previous plane's buffer

    int pcbase = 0;
    auto body = [&](auto uc) {
        constexpr int U = decltype(uc)::value;
        const int p = pcbase + U;
        const int d = od0 - RAD + p;
        const bool dval = (p < NPLANES) && ((unsigned)d < (unsigned)DD);  // block-uniform

        // ---- issue async staging of plane p+1 into raw[(p+1)&1] (overlaps phase 1) ----
        {
            const int pn = p + 1;
            const int dn = od0 - RAD + pn;
            if ((pn < NPLANES) && ((unsigned)dn < (unsigned)DD)) stage(pn, dn);
        }

        // ---- phase 1: W-conv of 5 stats from LDS raw (threads 0..103) ----
        if (dval && p1r < HALO_H) {
            const int rswz = p1r & 7;
            const float* r1 = raw + (p & 1) * RAWF + p1r * 32;   // img1 row base
            const float* r2 = r1 + 832;                          // img2 block (+208 slots)
            float t1[4]  = {0.f,0.f,0.f,0.f};
            float t2[4]  = {0.f,0.f,0.f,0.f};
            float t11[4] = {0.f,0.f,0.f,0.f};
            float t22[4] = {0.f,0.f,0.f,0.f};
            float t12[4] = {0.f,0.f,0.f,0.f};
#pragma unroll
            for (int j = 0; j < 5; ++j) {
                const int qo = ((p1q + j) ^ rswz) << 2;          // swizzled quad, floats
                const f4 va = *(const f4*)(r1 + qo);
                const f4 vb = *(const f4*)(r2 + qo);
#pragma unroll
                for (int ii = 0; ii < 4; ++ii) {
                    const int i = 4 * j + ii;          // window col 0..19; need 3..16
                    if (i < 3 || i > 16) continue;
                    const float av = va[ii], bv = vb[ii];
                    const float aa = av * av, bb2 = bv * bv, ab = av * bv;
#pragma unroll
                    for (int m = 0; m < 4; ++m) {
                        const int k = i - m - 3;       // tap index (compile-time)
                        if (k >= 0 && k < KK) {
                            const float w = gw.g[k];   // SGPR (kernarg)
                            t1[m]  += w * av;
                            t2[m]  += w * bv;
                            t11[m] += w * aa;
                            t22[m] += w * bb2;
                            t12[m] += w * ab;
                        }
                    }
                }
            }
            float* tw = twr + p1r * TS + 4 * p1q;      // 16B-aligned
            f4 v;
            v[0]=t1[0];  v[1]=t1[1];  v[2]=t1[2];  v[3]=t1[3];  *(f4*)(tw + 0*STAT) = v;
            v[0]=t2[0];  v[1]=t2[1];  v[2]=t2[2];  v[3]=t2[3];  *(f4*)(tw + 1*STAT) = v;
            v[0]=t11[0]; v[1]=t11[1]; v[2]=t11[2]; v[3]=t11[3]; *(f4*)(tw + 2*STAT) = v;
            v[0]=t22[0]; v[1]=t22[1]; v[2]=t22[2]; v[3]=t22[3]; *(f4*)(tw + 3*STAT) = v;
            v[0]=t12[0]; v[1]=t12[1]; v[2]=t12[2]; v[3]=t12[3]; *(f4*)(tw + 4*STAT) = v;
        }

        // unconditional: tmp write->read ordering AND drains staged loads (vmcnt(0))
        __syncthreads();

        // ---- phase 2: H-conv (scalar) + static-slot D scatter ----
        if (dval) {
            float P1 = 0.f, P2 = 0.f, P11 = 0.f, P22 = 0.f, P12 = 0.f;
            const float* tb = twr + (ty * TS + xc);
#pragma unroll
            for (int k = 0; k < KK; ++k) {
                const float w = gw.g[k];
                const int o = k * TS;
                P1  += w * tb[0*STAT + o];
                P2  += w * tb[1*STAT + o];
                P11 += w * tb[2*STAT + o];
                P22 += w * tb[3*STAT + o];
                P12 += w * tb[4*STAT + o];
            }
#pragma unroll
            for (int t = 0; t < KK; ++t) {
                constexpr int base = U + 22;
                const int s = (base - t) % 11;         // compile-time fold
                const float w = gw.g[t];
                a1[s]  += w * P1;
                a2[s]  += w * P2;
                a11[s] += w * P11;
                a22[s] += w * P22;
                a12[s] += w * P12;
            }
        }

        // ---- emit output q = p-10 from fixed slot (U+1)%11, then zero it ----
        constexpr int e = (U + 1) % 11;
        if (p >= 2 * RAD && p < NPLANES) {
            float mu1 = a1[e], mu2 = a2[e];
            float m11 = mu1 * mu1, m22 = mu2 * mu2, m12 = mu1 * mu2;
            float sg1 = a11[e] - m11, sg2 = a22[e] - m22, sg12 = a12[e] - m12;
            const float C1c = 0.0001f, C2c = 0.0009f;
            float num = (2.f * m12 + C1c) * (2.f * sg12 + C2c);
            float den = (m11 + m22 + C1c) * (sg1 + sg2 + C2c);
            lsum += num / den;
        }
        a1[e] = 0.f; a2[e] = 0.f; a11[e] = 0.f; a22[e] = 0.f; a12[e] = 0.f;

        // swap tmp double buffers
        float* t = twr; twr = trd; trd = t;
    };

    for (pcbase = 0; pcbase < 44; pcbase += 11) {
        body(std::integral_constant<int, 0>{});
        body(std::integral_constant<int, 1>{});
        body(std::integral_constant<int, 2>{});
        body(std::integral_constant<int, 3>{});
        body(std::integral_constant<int, 4>{});
        body(std::integral_constant<int, 5>{});
        body(std::integral_constant<int, 6>{});
        body(std::integral_constant<int, 7>{});
        body(std::integral_constant<int, 8>{});
        body(std::integral_constant<int, 9>{});
        body(std::integral_constant<int, 10>{});
    }

    // ---- reduction: wave shuffle -> LDS -> one atomic per block ----
    float v = lsum;
#pragma unroll
    for (int off = 32; off > 0; off >>= 1)
        v += __shfl_down(v, off, 64);
    if ((tid & 63) == 0) wsum[tid >> 6] = v;
    __syncthreads();
    if (tid == 0) {
        const float inv_n = 1.0f / ((float)BB * DD * HH * WW);
        atomicAdd(out, (wsum[0] + wsum[1] + wsum[2] + wsum[3]) * inv_n);
    }
}

extern "C" void kernel_launch(void* const* d_in, const int* in_sizes, int n_in,
                              void* d_out, int out_size, void* d_ws, size_t ws_size,
                              hipStream_t stream) {
    const float* img1 = (const float*)d_in[0];
    const float* img2 = (const float*)d_in[1];
    float* out = (float*)d_out;

    GaussW gw;
    double gd[KK], sum = 0.0;
    for (int i = 0; i < KK; ++i) {
        double x = (double)(i - KK / 2);
        gd[i] = exp(-(x * x) / (2.0 * 1.5 * 1.5));
        sum += gd[i];
    }
    for (int i = 0; i < KK; ++i) gw.g[i] = (float)(gd[i] / sum);

    hipMemsetAsync(d_out, 0, sizeof(float), stream);

    dim3 grid(10 * 10 * NDCH * BB);   // 2000 blocks
    dim3 block(256);                  // 4 waves
    hipLaunchKernelGGL(ssim3d_kernel, grid, block, 0, stream,
                       img1, img2, out, gw);
}